// Round 8
// baseline (493.554 us; speedup 1.0000x reference)
//
#include <hip/hip_runtime.h>
#include <hip/hip_bf16.h>

typedef __attribute__((ext_vector_type(8))) __bf16 bf16x8;
typedef __attribute__((ext_vector_type(8))) short short8;
typedef __attribute__((ext_vector_type(4))) float floatx4;
typedef __attribute__((ext_vector_type(4))) int intx4;
typedef unsigned short u16;
typedef unsigned int u32;
typedef unsigned long long u64;

constexpr int BB = 2, NN = 4096, DD = 256;
constexpr int NCHUNK = 8;                  // flash column chunks
constexpr int KSTEP = 32;                  // flash K-tile rows per step
constexpr int CHUNKLEN = NN / NCHUNK;      // 512
constexpr int STEPS = CHUNKLEN / KSTEP;    // 16
constexpr int LOBE = 2 * 1024 * 1024;      // u16 elems between hi/lo buffers (4MB/2)
constexpr float SLOPE = 0.2f;
constexpr float NEGINF = -9e15f;

#define DEVI static __device__ __forceinline__

DEVI u16 f2bf(float f) {
  u32 u = __float_as_uint(f);
  u += 0x7fffu + ((u >> 16) & 1u);
  return (u16)(u >> 16);
}
DEVI float bf2f(u16 h) { return __uint_as_float(((u32)h) << 16); }
DEVI float lrelu(float x) { return x > 0.f ? x : SLOPE * x; }

DEVI floatx4 mfma16(short8 a, short8 b, floatx4 c) {
  return __builtin_amdgcn_mfma_f32_16x16x32_bf16(
      __builtin_bit_cast(bf16x8, a), __builtin_bit_cast(bf16x8, b), c, 0, 0, 0);
}

// async global->LDS, 16B per lane. LDS dest must be wave-uniform (HW adds
// lane*16); per-lane swizzle goes on the GLOBAL address (XOR involution).
DEVI void gload16(const void* g, void* l) {
  __builtin_amdgcn_global_load_lds(
      (const __attribute__((address_space(1))) void*)g,
      (__attribute__((address_space(3))) void*)l, 16, 0, 0);
}

// ---------------------------------------------------------------------------
// K0: transpose + hi/lo split of the three 256x256 weight matrices
// grid (8,8,3), block (32,8)
__global__ void k_prep_w(const float* W, const float* A12, const float* I1,
                         u16* WThi, u16* WTlo, u16* A12Thi, u16* A12Tlo,
                         u16* I1Thi, u16* I1Tlo) {
  __shared__ float tile[32][33];
  const float* src = blockIdx.z == 0 ? W : (blockIdx.z == 1 ? A12 : I1);
  u16* dhi = blockIdx.z == 0 ? WThi : (blockIdx.z == 1 ? A12Thi : I1Thi);
  u16* dlo = blockIdx.z == 0 ? WTlo : (blockIdx.z == 1 ? A12Tlo : I1Tlo);
  int k0 = blockIdx.x * 32, n0 = blockIdx.y * 32;
  int tx = threadIdx.x, ty = threadIdx.y;
  #pragma unroll
  for (int r = 0; r < 4; r++)
    tile[ty + r * 8][tx] = src[(size_t)(k0 + ty + r * 8) * 256 + n0 + tx];
  __syncthreads();
  #pragma unroll
  for (int r = 0; r < 4; r++) {
    float v = tile[tx][ty + r * 8];  // = src[k0+tx][n0+ty+r*8]
    u16 hb = f2bf(v);
    size_t o = (size_t)(n0 + ty + r * 8) * 256 + k0 + tx;
    dhi[o] = hb;
    dlo[o] = f2bf(v - bf2f(hb));
  }
}

// ---------------------------------------------------------------------------
// K7: transpose e1w/e2w (256x16 -> 16x256) so the MLP's weight loads coalesce.
// grid 2, block 256.
__global__ void k_prep_e(const float* e1w, const float* e2w, float* e1t,
                         float* e2t) {
  int t = threadIdx.x;
  const float* src = blockIdx.x == 0 ? e1w : e2w;
  float* dst = blockIdx.x == 0 ? e1t : e2t;
  float v[16];
  #pragma unroll
  for (int o = 0; o < 16; o++) v[o] = src[t * 16 + o];
  #pragma unroll
  for (int o = 0; o < 16; o++) dst[o * 256 + t] = v[o];
}

// ---------------------------------------------------------------------------
// K6: pack adj (int 0/1) into bitmask. Each wave: 256 ints -> 4 u64 words.
// grid 32768, block 256.
__global__ void k_adjpack(const int* adj, u64* maskp) {
  int wave = (blockIdx.x * 256 + threadIdx.x) >> 6;
  int lane = threadIdx.x & 63;
  size_t base = (size_t)wave * 256;
  const int* p = adj + base;
  u64 m[4];
  #pragma unroll
  for (int r = 0; r < 4; r++) {
    int v = p[r * 64 + lane];
    m[r] = __ballot(v > 0);
  }
  if (lane < 4) {
    u64 sel = lane == 0 ? m[0] : lane == 1 ? m[1] : lane == 2 ? m[2] : m[3];
    maskp[base / 64 + lane] = sel;
  }
}

// ---------------------------------------------------------------------------
// Generic 8192x256 @ 256x256 GEMM, bf16x3, with B-tile staged in LDS
// (XOR-swizzled so ds_read_b128 is conflict-free).
// AMODE 0: A f32; 1: A hi/lo bf16. EPI 0: hi/lo bf16 out. EPI 1: bias+lrelu f32.
// grid (128,8), block 256 (4 waves; wave = 16 rows x 32 cols)
template <int AMODE, int EPI>
__global__ __launch_bounds__(256) void k_gemm(
    const float* Af32, const u16* Ahi, const u16* Alo,
    const u16* BThi, const u16* BTlo,
    u16* Ohi, u16* Olo, float* Of32, const float* bias) {
  int t = threadIdx.x;
  int wid = t >> 6, lane = t & 63;
  int li = lane & 15, lg = lane >> 4;
  int row0 = blockIdx.x * 64 + wid * 16;
  int col0 = blockIdx.y * 32;
  int arow = row0 + li;

  __shared__ __align__(16) u16 Bh[32 * 256];
  __shared__ __align__(16) u16 Bl[32 * 256];
  // stage B^T[col0..col0+32][256] hi+lo, swizzled
  #pragma unroll
  for (int s = 0; s < 4; s++) {
    int r = s * 8 + (t >> 5), c8 = (t & 31) * 8;
    int off = r * 256 + (c8 ^ ((r & 7) << 3));
    *(intx4*)(Bh + off) = *(const intx4*)(BThi + (size_t)(col0 + r) * DD + c8);
    *(intx4*)(Bl + off) = *(const intx4*)(BTlo + (size_t)(col0 + r) * DD + c8);
  }

  short8 ahi[8], alo[8];
  if constexpr (AMODE == 0) {
    const float* ap = Af32 + (size_t)arow * DD + lg * 8;
    #pragma unroll
    for (int ks = 0; ks < 8; ks++) {
      floatx4 f0 = *(const floatx4*)(ap + ks * 32);
      floatx4 f1 = *(const floatx4*)(ap + ks * 32 + 4);
      short8 h, l;
      #pragma unroll
      for (int e = 0; e < 4; e++) {
        u16 hb = f2bf(f0[e]); h[e] = (short)hb; l[e] = (short)f2bf(f0[e] - bf2f(hb));
        u16 hb2 = f2bf(f1[e]); h[e + 4] = (short)hb2; l[e + 4] = (short)f2bf(f1[e] - bf2f(hb2));
      }
      ahi[ks] = h; alo[ks] = l;
    }
  } else {
    const u16* ap = Ahi + (size_t)arow * DD + lg * 8;
    const u16* ap2 = Alo + (size_t)arow * DD + lg * 8;
    #pragma unroll
    for (int ks = 0; ks < 8; ks++) {
      ahi[ks] = *(const short8*)(ap + ks * 32);
      alo[ks] = *(const short8*)(ap2 + ks * 32);
    }
  }
  __syncthreads();

  floatx4 acc[2];
  #pragma unroll
  for (int cf = 0; cf < 2; cf++) acc[cf] = 0.f;

  #pragma unroll
  for (int cf = 0; cf < 2; cf++) {
    int row = cf * 16 + li;
    int rsw = (row & 7) << 3;
    #pragma unroll
    for (int ks = 0; ks < 8; ks++) {
      int off = row * 256 + ((ks * 32 + lg * 8) ^ rsw);
      short8 bhf = *(const short8*)(Bh + off);
      short8 blf = *(const short8*)(Bl + off);
      acc[cf] = mfma16(ahi[ks], bhf, acc[cf]);
      acc[cf] = mfma16(alo[ks], bhf, acc[cf]);
      acc[cf] = mfma16(ahi[ks], blf, acc[cf]);
    }
  }

  #pragma unroll
  for (int cf = 0; cf < 2; cf++) {
    int col = col0 + cf * 16 + li;
    #pragma unroll
    for (int r = 0; r < 4; r++) {
      int row = row0 + lg * 4 + r;
      float v = acc[cf][r];
      if constexpr (EPI == 0) {
        u16 hb = f2bf(v);
        Ohi[(size_t)row * DD + col] = hb;
        Olo[(size_t)row * DD + col] = f2bf(v - bf2f(hb));
      } else {
        v += bias[col];
        v = lrelu(v);
        Of32[(size_t)row * DD + col] = v;
      }
    }
  }
}

// ---------------------------------------------------------------------------
// K2: ax[row]=h.a1, ay[row]=h.a2 (h = hi+lo). grid 2048, block 256 (wave/row)
__global__ void k_axay(const u16* h_hi, const u16* h_lo, const float* a1,
                       const float* a2, float* ax, float* ay) {
  int row = blockIdx.x * 4 + (threadIdx.x >> 6);
  int lane = threadIdx.x & 63;
  ushort4 hw = *(const ushort4*)(h_hi + (size_t)row * DD + lane * 4);
  ushort4 lw = *(const ushort4*)(h_lo + (size_t)row * DD + lane * 4);
  floatx4 av1 = *(const floatx4*)(a1 + lane * 4);
  floatx4 av2 = *(const floatx4*)(a2 + lane * 4);
  const u16* hp = (const u16*)&hw;
  const u16* lp = (const u16*)&lw;
  float s1 = 0.f, s2 = 0.f;
  #pragma unroll
  for (int r = 0; r < 4; r++) {
    float hv = bf2f(hp[r]) + bf2f(lp[r]);
    s1 += hv * av1[r];
    s2 += hv * av2[r];
  }
  #pragma unroll
  for (int off = 32; off; off >>= 1) {
    s1 += __shfl_xor(s1, off);
    s2 += __shfl_xor(s2, off);
  }
  if (lane == 0) { ax[row] = s1; ay[row] = s2; }
}

// ---------------------------------------------------------------------------
// K1: featT[b][d][n] = bf16(feat[b][n][d]).  grid (64,4,2), block 256
__global__ void k_featT(const float* feat, u16* featT) {
  __shared__ float tile[64][65];
  int b = blockIdx.z, n0 = blockIdx.x * 64, d0 = blockIdx.y * 64;
  int tx = threadIdx.x & 63, ty = threadIdx.x >> 6;
  #pragma unroll
  for (int r = 0; r < 16; r++) {
    int n = ty + r * 4;
    tile[n][tx] = feat[((size_t)b * NN + n0 + n) * DD + d0 + tx];
  }
  __syncthreads();
  #pragma unroll
  for (int r = 0; r < 16; r++) {
    int d = ty + r * 4;
    featT[((size_t)b * DD + d0 + d) * NN + n0 + tx] = f2bf(tile[tx][d]);
  }
}

// ---------------------------------------------------------------------------
// K3: flash attention; K/V staged via global_load_lds (pre-swizzled sources,
// linear LDS dest). No staging VGPRs -> 3 waves/SIMD (3 WGs/CU, LDS 53.8KB).
// Q=t, K=h (bf16x3), V=featT (bf16). S^T frags; softmax row in 4 lanes.
// grid (64 row-tiles, NCHUNK, 2), block 256 = 4 waves sharing LDS tiles.
__global__ __launch_bounds__(256, 3) void k_flash(
    const u16* t_hi, const u16* h_hi, const u16* featT,
    const float* ax, const float* ay, const u64* maskp,
    float* PO, float* m_ws, float* l_ws) {
  const u16* t_lo = t_hi + LOBE;   // hi/lo carved back-to-back (4MB apart)
  int b = blockIdx.z, chunk = blockIdx.y, it = blockIdx.x;
  int t = threadIdx.x;
  int wid = t >> 6, lane = t & 63;
  int li = lane & 15, lg = lane >> 4;
  int i = it * 64 + wid * 16 + li;            // this lane's query row
  size_t browQ = (size_t)b * NN + i;

  __shared__ __align__(16) u16 Ks[2][KSTEP * 256];  // hi, lo: 32 KB, swizzled
  __shared__ __align__(16) u16 Vs[256 * KSTEP];     // 16 KB, swizzled
  __shared__ __align__(16) u16 Pbuf[4][16][36];     // per-wave P exchange

  short8 qhi[8], qlo[8];
  {
    const u16* qp = t_hi + browQ * DD + lg * 8;
    const u16* qp2 = t_lo + browQ * DD + lg * 8;
    #pragma unroll
    for (int ks = 0; ks < 8; ks++) {
      qhi[ks] = *(const short8*)(qp + ks * 32);
      qlo[ks] = *(const short8*)(qp2 + ks * 32);
    }
  }
  float ayv = ay[browQ];
  const float* axp = ax + (size_t)b * NN;
  const u32* mrow = (const u32*)maskp + browQ * (NN / 32);
  const u16* kh_src = h_hi + ((size_t)b * NN + chunk * CHUNKLEN) * DD;
  const u16* v_src = featT + (size_t)b * DD * NN + chunk * CHUNKLEN;

  floatx4 acc[16];
  #pragma unroll
  for (int df = 0; df < 16; df++) acc[df] = 0.f;
  float m_run = -INFINITY, l_run = 0.f;

  for (int jt = 0; jt < STEPS; jt++) {
    int j0 = jt * KSTEP;
    // ---- stage tile jt via global_load_lds (buffer free: barrier below) ----
    {
      const u16* khp = kh_src + (size_t)j0 * DD;
      int l5 = lane >> 5, l31 = lane & 31;
      #pragma unroll
      for (int s = 0; s < 4; s++) {
        int r0 = wid * 8 + s * 2;
        int row = r0 + l5;
        const u16* g = khp + (size_t)row * DD + ((l31 * 8) ^ ((row & 7) << 3));
        gload16(g, &Ks[0][r0 * 256]);
        gload16(g + LOBE, &Ks[1][r0 * 256]);
      }
      int l2 = lane >> 2, lc = (lane & 3) * 8;
      #pragma unroll
      for (int s = 0; s < 4; s++) {
        int d0 = wid * 64 + s * 16;
        int d = d0 + l2;
        const u16* g = v_src + (size_t)d * NN + j0 + (lc ^ (((d >> 1) & 3) << 3));
        gload16(g, &Vs[d0 * KSTEP]);
      }
    }
    // independent loads: latency hides under the staging drain
    int ja = chunk * CHUNKLEN + j0;
    u32 M = mrow[ja >> 5];
    floatx4 axv0 = *(const floatx4*)(axp + ja + lg * 4);
    floatx4 axv1 = *(const floatx4*)(axp + ja + 16 + lg * 4);
    __syncthreads();  // drains vmcnt -> tile visible to all waves

    // ---- S^T = K . Q^T  (bf16x3) from LDS ----
    floatx4 sacc[2];
    sacc[0] = 0.f; sacc[1] = 0.f;
    #pragma unroll
    for (int ks = 0; ks < 8; ks++) {
      #pragma unroll
      for (int fi = 0; fi < 2; fi++) {
        int row = fi * 16 + li;
        int off = row * 256 + ((ks * 32 + lg * 8) ^ ((row & 7) << 3));
        short8 a0 = *(const short8*)(&Ks[0][off]);
        short8 a1 = *(const short8*)(&Ks[1][off]);
        sacc[fi] = mfma16(a0, qhi[ks], sacc[fi]);
        sacc[fi] = mfma16(a1, qhi[ks], sacc[fi]);
        sacc[fi] = mfma16(a0, qlo[ks], sacc[fi]);
      }
    }
    // ---- bias + lrelu + mask; online softmax ----
    float sv[2][4];
    float m_tile = -INFINITY;
    #pragma unroll
    for (int fi = 0; fi < 2; fi++) {
      u32 nib = (M >> (fi * 16 + lg * 4)) & 0xFu;
      floatx4 axv = fi == 0 ? axv0 : axv1;
      #pragma unroll
      for (int r = 0; r < 4; r++) {
        float s = sacc[fi][r] + axv[r] + ayv;
        s = lrelu(s);
        s = (nib >> r) & 1u ? s : NEGINF;
        sv[fi][r] = s;
        m_tile = fmaxf(m_tile, s);
      }
    }
    m_tile = fmaxf(m_tile, __shfl_xor(m_tile, 16));
    m_tile = fmaxf(m_tile, __shfl_xor(m_tile, 32));
    bool nores = __all(m_tile <= m_run);  // exact skip: max unchanged
    if (!nores) {
      float m_new = fmaxf(m_run, m_tile);
      float scale = __expf(m_run - m_new);
      l_run *= scale;
      #pragma unroll
      for (int df = 0; df < 16; df++) acc[df] *= scale;
      m_run = m_new;
    }

    float psum = 0.f;
    #pragma unroll
    for (int fi = 0; fi < 2; fi++) {
      u16 pb[4];
      #pragma unroll
      for (int r = 0; r < 4; r++) {
        float p = __expf(sv[fi][r] - m_run);
        pb[r] = f2bf(p);
        psum += bf2f(pb[r]);
      }
      u32 w0 = (u32)pb[0] | ((u32)pb[1] << 16);
      u32 w1 = (u32)pb[2] | ((u32)pb[3] << 16);
      *(uint2*)&Pbuf[wid][li][fi * 16 + lg * 4] = make_uint2(w0, w1);
    }
    psum += __shfl_xor(psum, 16);
    psum += __shfl_xor(psum, 32);
    l_run += psum;

    // ---- PV: O^T += V^T . P^T  (V from LDS) ----
    short8 pf = *(const short8*)&Pbuf[wid][li][lg * 8];
    #pragma unroll
    for (int df = 0; df < 16; df++) {
      int d = df * 16 + li;
      short8 vf = *(const short8*)(&Vs[d * KSTEP + ((lg * 8) ^ (((d >> 1) & 3) << 3))]);
      acc[df] = mfma16(vf, pf, acc[df]);
    }
    __syncthreads();  // all waves done reading before next overwrite
  }

  // ---- partials out: PO[b][chunk][i][d], float4 per (df) ----
  size_t pobase = ((size_t)(b * NCHUNK + chunk) * NN + i) * DD;
  #pragma unroll
  for (int df = 0; df < 16; df++)
    *(floatx4*)(PO + pobase + df * 16 + lg * 4) = acc[df];
  if (lg == 0) {
    size_t mi = ((size_t)b * NCHUNK + chunk) * NN + i;
    m_ws[mi] = m_run;
    l_ws[mi] = l_run;
  }
}

// ---------------------------------------------------------------------------
// K5: combine NCHUNK partials -> h_prime row (registers) -> BiInteraction MLP
// -> c (hi/lo bf16). Weights pre-transposed so loads coalesce.
// grid (1024,2), block 256 (wave per row).
__global__ void k_combine_mlp(const float* PO, const float* m_ws,
                              const float* l_ws, const float* feat,
                              const float* e1t, const float* e1b,
                              const float* e2t, const float* e2b,
                              const float* i0w, const float* i0b,
                              u16* c_hi, u16* c_lo) {
  int b = blockIdx.y;
  int t = threadIdx.x;
  int i = blockIdx.x * 4 + (t >> 6);
  int lane = t & 63;
  int d4 = lane * 4;
  size_t row = (size_t)b * NN + i;

  // ---- combine ----
  float mc[NCHUNK], lc[NCHUNK];
  #pragma unroll
  for (int c = 0; c < NCHUNK; c++) {
    mc[c] = m_ws[((size_t)b * NCHUNK + c) * NN + i];
    lc[c] = l_ws[((size_t)b * NCHUNK + c) * NN + i];
  }
  float M = -INFINITY;
  #pragma unroll
  for (int c = 0; c < NCHUNK; c++) M = fmaxf(M, mc[c]);
  float w[NCHUNK], L = 0.f;
  #pragma unroll
  for (int c = 0; c < NCHUNK; c++) { w[c] = __expf(mc[c] - M); L += w[c] * lc[c]; }
  float invL = 1.f / L;

  floatx4 hv = 0.f;
  #pragma unroll
  for (int c = 0; c < NCHUNK; c++) {
    floatx4 v = *(const floatx4*)(PO + ((size_t)(b * NCHUNK + c) * NN + i) * DD + d4);
    hv += w[c] * v;
  }
  hv *= invL;  // h_prime[row][d4..d4+3], stays in registers

  // ---- BiInteraction MLP (coalesced transposed weights) ----
  floatx4 fv = *(const floatx4*)(feat + row * DD + d4);
  float p1[16], p2[16];
  #pragma unroll
  for (int o = 0; o < 16; o++) {
    floatx4 w1 = *(const floatx4*)(e1t + o * 256 + d4);
    floatx4 w2 = *(const floatx4*)(e2t + o * 256 + d4);
    p1[o] = fv[0] * w1[0] + fv[1] * w1[1] + fv[2] * w1[2] + fv[3] * w1[3];
    p2[o] = hv[0] * w2[0] + hv[1] * w2[1] + hv[2] * w2[2] + hv[3] * w2[3];
  }
  #pragma unroll
  for (int off = 32; off; off >>= 1) {
    #pragma unroll
    for (int o = 0; o < 16; o++) {
      p1[o] += __shfl_xor(p1[o], off);
      p2[o] += __shfl_xor(p2[o], off);
    }
  }
  float cc[32];
  #pragma unroll
  for (int o = 0; o < 16; o++) {
    cc[o] = lrelu(p1[o] + e1b[o]);
    cc[16 + o] = lrelu(p2[o] + e2b[o]);
  }
  #pragma unroll
  for (int q = 0; q < 4; q++) {
    int o2 = q * 64 + lane;
    float s = i0b[o2];
    #pragma unroll
    for (int k = 0; k < 32; k++) s += cc[k] * i0w[(size_t)k * 256 + o2];
    s = lrelu(s);
    u16 hb = f2bf(s);
    c_hi[row * DD + o2] = hb;
    c_lo[row * DD + o2] = f2bf(s - bf2f(hb));
  }
}

// ---------------------------------------------------------------------------
extern "C" void kernel_launch(void* const* d_in, const int* in_sizes, int n_in,
                              void* d_out, int out_size, void* d_ws,
                              size_t ws_size, hipStream_t stream) {
  const float* feat = (const float*)d_in[0];
  const int* adj = (const int*)d_in[1];
  const float* W = (const float*)d_in[2];
  const float* a1 = (const float*)d_in[3];
  const float* a2 = (const float*)d_in[4];
  const float* a12 = (const float*)d_in[5];
  const float* e1w = (const float*)d_in[6];
  const float* e1b = (const float*)d_in[7];
  const float* e2w = (const float*)d_in[8];
  const float* e2b = (const float*)d_in[9];
  const float* i0w = (const float*)d_in[10];
  const float* i0b = (const float*)d_in[11];
  const float* i1w = (const float*)d_in[12];
  const float* i1b = (const float*)d_in[13];
  float* out = (float*)d_out;

  char* p = (char*)d_ws;
  auto carve = [&](size_t bytes) -> char* {
    char* r = p;
    p += (bytes + 255) & ~(size_t)255;
    return r;
  };
  const size_t MAT = 256 * 256 * sizeof(u16);             // 128 KB
  const size_t BND = (size_t)BB * NN * DD * sizeof(u16);  // 4 MB
  u16* WThi = (u16*)carve(MAT);
  u16* WTlo = (u16*)carve(MAT);
  u16* A12Thi = (u16*)carve(MAT);
  u16* A12Tlo = (u16*)carve(MAT);
  u16* I1Thi = (u16*)carve(MAT);
  u16* I1Tlo = (u16*)carve(MAT);
  u16* h_hi = (u16*)carve(BND);   // h_lo must be exactly LOBE elems after h_hi
  u16* h_lo = (u16*)carve(BND);
  u16* t_hi = (u16*)carve(BND);
  u16* t_lo = (u16*)carve(BND);
  u16* featT = (u16*)carve(BND);
  float* ax = (float*)carve((size_t)BB * NN * 4);
  float* ay = (float*)carve((size_t)BB * NN * 4);
  u64* maskp = (u64*)carve((size_t)BB * NN * (NN / 64) * 8);     // 4.2 MB
  float* PO = (float*)carve((size_t)BB * NCHUNK * NN * DD * 4);  // 67 MB
  float* m_ws = (float*)carve((size_t)BB * NCHUNK * NN * 4);
  float* l_ws = (float*)carve((size_t)BB * NCHUNK * NN * 4);
  float* e1t = (float*)carve(256 * 16 * 4);
  float* e2t = (float*)carve(256 * 16 * 4);
  u16* c_hi = (u16*)carve(BND);
  u16* c_lo = (u16*)carve(BND);

  k_adjpack<<<32768, 256, 0, stream>>>(adj, maskp);
  k_prep_w<<<dim3(8, 8, 3), dim3(32, 8), 0, stream>>>(
      W, a12, i1w, WThi, WTlo, A12Thi, A12Tlo, I1Thi, I1Tlo);
  k_prep_e<<<2, 256, 0, stream>>>(e1w, e2w, e1t, e2t);
  k_gemm<0, 0><<<dim3(128, 8), 256, 0, stream>>>(
      feat, nullptr, nullptr, WThi, WTlo, h_hi, h_lo, nullptr, nullptr);
  k_axay<<<2048, 256, 0, stream>>>(h_hi, h_lo, a1, a2, ax, ay);
  k_gemm<1, 0><<<dim3(128, 8), 256, 0, stream>>>(
      nullptr, h_hi, h_lo, A12Thi, A12Tlo, t_hi, t_lo, nullptr, nullptr);
  k_featT<<<dim3(64, 4, 2), 256, 0, stream>>>(feat, featT);
  k_flash<<<dim3(64, NCHUNK, 2), 256, 0, stream>>>(
      t_hi, h_hi, featT, ax, ay, maskp, PO, m_ws, l_ws);
  k_combine_mlp<<<dim3(1024, 2), 256, 0, stream>>>(
      PO, m_ws, l_ws, feat, e1t, e1b, e2t, e2b, i0w, i0b, c_hi, c_lo);
  k_gemm<1, 1><<<dim3(128, 8), 256, 0, stream>>>(
      nullptr, c_hi, c_lo, I1Thi, I1Tlo, nullptr, nullptr, out, i1b);
}

// Round 9
// 387.004 us; speedup vs baseline: 1.2753x; 1.2753x over previous
//
#include <hip/hip_runtime.h>
#include <hip/hip_bf16.h>

typedef __attribute__((ext_vector_type(8))) __bf16 bf16x8;
typedef __attribute__((ext_vector_type(8))) short short8;
typedef __attribute__((ext_vector_type(4))) float floatx4;
typedef __attribute__((ext_vector_type(4))) int intx4;
typedef unsigned short u16;
typedef unsigned int u32;
typedef unsigned long long u64;

constexpr int BB = 2, NN = 4096, DD = 256;
constexpr int NCHUNK = 4;                  // flash column chunks
constexpr int KSTEP = 32;                  // flash K-tile rows per step
constexpr int CHUNKLEN = NN / NCHUNK;      // 1024
constexpr int STEPS = CHUNKLEN / KSTEP;    // 32
constexpr float SLOPE = 0.2f;
constexpr float NEGINF = -9e15f;

#define DEVI static __device__ __forceinline__

DEVI u16 f2bf(float f) {
  u32 u = __float_as_uint(f);
  u += 0x7fffu + ((u >> 16) & 1u);
  return (u16)(u >> 16);
}
DEVI float bf2f(u16 h) { return __uint_as_float(((u32)h) << 16); }
DEVI float lrelu(float x) { return x > 0.f ? x : SLOPE * x; }

DEVI floatx4 mfma16(short8 a, short8 b, floatx4 c) {
  return __builtin_amdgcn_mfma_f32_16x16x32_bf16(
      __builtin_bit_cast(bf16x8, a), __builtin_bit_cast(bf16x8, b), c, 0, 0, 0);
}

// ---------------------------------------------------------------------------
// K0: transpose + hi/lo split of the three 256x256 weight matrices
// grid (8,8,3), block (32,8)
__global__ void k_prep_w(const float* W, const float* A12, const float* I1,
                         u16* WThi, u16* WTlo, u16* A12Thi, u16* A12Tlo,
                         u16* I1Thi, u16* I1Tlo) {
  __shared__ float tile[32][33];
  const float* src = blockIdx.z == 0 ? W : (blockIdx.z == 1 ? A12 : I1);
  u16* dhi = blockIdx.z == 0 ? WThi : (blockIdx.z == 1 ? A12Thi : I1Thi);
  u16* dlo = blockIdx.z == 0 ? WTlo : (blockIdx.z == 1 ? A12Tlo : I1Tlo);
  int k0 = blockIdx.x * 32, n0 = blockIdx.y * 32;
  int tx = threadIdx.x, ty = threadIdx.y;
  #pragma unroll
  for (int r = 0; r < 4; r++)
    tile[ty + r * 8][tx] = src[(size_t)(k0 + ty + r * 8) * 256 + n0 + tx];
  __syncthreads();
  #pragma unroll
  for (int r = 0; r < 4; r++) {
    float v = tile[tx][ty + r * 8];  // = src[k0+tx][n0+ty+r*8]
    u16 hb = f2bf(v);
    size_t o = (size_t)(n0 + ty + r * 8) * 256 + k0 + tx;
    dhi[o] = hb;
    dlo[o] = f2bf(v - bf2f(hb));
  }
}

// ---------------------------------------------------------------------------
// K7: transpose e1w/e2w (256x16 -> 16x256) so the MLP's weight loads coalesce.
// grid 2, block 256.
__global__ void k_prep_e(const float* e1w, const float* e2w, float* e1t,
                         float* e2t) {
  int t = threadIdx.x;
  const float* src = blockIdx.x == 0 ? e1w : e2w;
  float* dst = blockIdx.x == 0 ? e1t : e2t;
  float v[16];
  #pragma unroll
  for (int o = 0; o < 16; o++) v[o] = src[t * 16 + o];
  #pragma unroll
  for (int o = 0; o < 16; o++) dst[o * 256 + t] = v[o];
}

// ---------------------------------------------------------------------------
// K6: pack adj (int 0/1) into bitmask. Each wave: 256 ints -> 4 u64 words.
// grid 32768, block 256.
__global__ void k_adjpack(const int* adj, u64* maskp) {
  int wave = (blockIdx.x * 256 + threadIdx.x) >> 6;
  int lane = threadIdx.x & 63;
  size_t base = (size_t)wave * 256;
  const int* p = adj + base;
  u64 m[4];
  #pragma unroll
  for (int r = 0; r < 4; r++) {
    int v = p[r * 64 + lane];
    m[r] = __ballot(v > 0);
  }
  if (lane < 4) {
    u64 sel = lane == 0 ? m[0] : lane == 1 ? m[1] : lane == 2 ? m[2] : m[3];
    maskp[base / 64 + lane] = sel;
  }
}

// ---------------------------------------------------------------------------
// Generic 8192x256 @ 256x256 GEMM, bf16x3, with B-tile staged in LDS
// (XOR-swizzled so ds_read_b128 is conflict-free).
// AMODE 0: A f32; 1: A hi/lo bf16. EPI 0: hi/lo bf16 out. EPI 1: bias+lrelu f32.
// grid (128,8), block 256 (4 waves; wave = 16 rows x 32 cols)
template <int AMODE, int EPI>
__global__ __launch_bounds__(256) void k_gemm(
    const float* Af32, const u16* Ahi, const u16* Alo,
    const u16* BThi, const u16* BTlo,
    u16* Ohi, u16* Olo, float* Of32, const float* bias) {
  int t = threadIdx.x;
  int wid = t >> 6, lane = t & 63;
  int li = lane & 15, lg = lane >> 4;
  int row0 = blockIdx.x * 64 + wid * 16;
  int col0 = blockIdx.y * 32;
  int arow = row0 + li;

  __shared__ __align__(16) u16 Bh[32 * 256];
  __shared__ __align__(16) u16 Bl[32 * 256];
  // stage B^T[col0..col0+32][256] hi+lo, swizzled
  #pragma unroll
  for (int s = 0; s < 4; s++) {
    int r = s * 8 + (t >> 5), c8 = (t & 31) * 8;
    int off = r * 256 + (c8 ^ ((r & 7) << 3));
    *(intx4*)(Bh + off) = *(const intx4*)(BThi + (size_t)(col0 + r) * DD + c8);
    *(intx4*)(Bl + off) = *(const intx4*)(BTlo + (size_t)(col0 + r) * DD + c8);
  }

  short8 ahi[8], alo[8];
  if constexpr (AMODE == 0) {
    const float* ap = Af32 + (size_t)arow * DD + lg * 8;
    #pragma unroll
    for (int ks = 0; ks < 8; ks++) {
      floatx4 f0 = *(const floatx4*)(ap + ks * 32);
      floatx4 f1 = *(const floatx4*)(ap + ks * 32 + 4);
      short8 h, l;
      #pragma unroll
      for (int e = 0; e < 4; e++) {
        u16 hb = f2bf(f0[e]); h[e] = (short)hb; l[e] = (short)f2bf(f0[e] - bf2f(hb));
        u16 hb2 = f2bf(f1[e]); h[e + 4] = (short)hb2; l[e + 4] = (short)f2bf(f1[e] - bf2f(hb2));
      }
      ahi[ks] = h; alo[ks] = l;
    }
  } else {
    const u16* ap = Ahi + (size_t)arow * DD + lg * 8;
    const u16* ap2 = Alo + (size_t)arow * DD + lg * 8;
    #pragma unroll
    for (int ks = 0; ks < 8; ks++) {
      ahi[ks] = *(const short8*)(ap + ks * 32);
      alo[ks] = *(const short8*)(ap2 + ks * 32);
    }
  }
  __syncthreads();

  floatx4 acc[2];
  #pragma unroll
  for (int cf = 0; cf < 2; cf++) acc[cf] = 0.f;

  #pragma unroll
  for (int cf = 0; cf < 2; cf++) {
    int row = cf * 16 + li;
    int rsw = (row & 7) << 3;
    #pragma unroll
    for (int ks = 0; ks < 8; ks++) {
      int off = row * 256 + ((ks * 32 + lg * 8) ^ rsw);
      short8 bhf = *(const short8*)(Bh + off);
      short8 blf = *(const short8*)(Bl + off);
      acc[cf] = mfma16(ahi[ks], bhf, acc[cf]);
      acc[cf] = mfma16(alo[ks], bhf, acc[cf]);
      acc[cf] = mfma16(ahi[ks], blf, acc[cf]);
    }
  }

  #pragma unroll
  for (int cf = 0; cf < 2; cf++) {
    int col = col0 + cf * 16 + li;
    #pragma unroll
    for (int r = 0; r < 4; r++) {
      int row = row0 + lg * 4 + r;
      float v = acc[cf][r];
      if constexpr (EPI == 0) {
        u16 hb = f2bf(v);
        Ohi[(size_t)row * DD + col] = hb;
        Olo[(size_t)row * DD + col] = f2bf(v - bf2f(hb));
      } else {
        v += bias[col];
        v = lrelu(v);
        Of32[(size_t)row * DD + col] = v;
      }
    }
  }
}

// ---------------------------------------------------------------------------
// K2: ax[row]=h.a1, ay[row]=h.a2 (h = hi+lo). grid 2048, block 256 (wave/row)
__global__ void k_axay(const u16* h_hi, const u16* h_lo, const float* a1,
                       const float* a2, float* ax, float* ay) {
  int row = blockIdx.x * 4 + (threadIdx.x >> 6);
  int lane = threadIdx.x & 63;
  ushort4 hw = *(const ushort4*)(h_hi + (size_t)row * DD + lane * 4);
  ushort4 lw = *(const ushort4*)(h_lo + (size_t)row * DD + lane * 4);
  floatx4 av1 = *(const floatx4*)(a1 + lane * 4);
  floatx4 av2 = *(const floatx4*)(a2 + lane * 4);
  const u16* hp = (const u16*)&hw;
  const u16* lp = (const u16*)&lw;
  float s1 = 0.f, s2 = 0.f;
  #pragma unroll
  for (int r = 0; r < 4; r++) {
    float hv = bf2f(hp[r]) + bf2f(lp[r]);
    s1 += hv * av1[r];
    s2 += hv * av2[r];
  }
  #pragma unroll
  for (int off = 32; off; off >>= 1) {
    s1 += __shfl_xor(s1, off);
    s2 += __shfl_xor(s2, off);
  }
  if (lane == 0) { ax[row] = s1; ay[row] = s2; }
}

// ---------------------------------------------------------------------------
// K1: featT[b][d][n] = bf16(feat[b][n][d]).  grid (64,4,2), block 256
__global__ void k_featT(const float* feat, u16* featT) {
  __shared__ float tile[64][65];
  int b = blockIdx.z, n0 = blockIdx.x * 64, d0 = blockIdx.y * 64;
  int tx = threadIdx.x & 63, ty = threadIdx.x >> 6;
  #pragma unroll
  for (int r = 0; r < 16; r++) {
    int n = ty + r * 4;
    tile[n][tx] = feat[((size_t)b * NN + n0 + n) * DD + d0 + tx];
  }
  __syncthreads();
  #pragma unroll
  for (int r = 0; r < 16; r++) {
    int d = ty + r * 4;
    featT[((size_t)b * DD + d0 + d) * NN + n0 + tx] = f2bf(tile[tx][d]);
  }
}

// ---------------------------------------------------------------------------
// K3: flash attention, LDS-staged K/V (reg-staged async prefetch, XOR swizzle)
// with XCD-bijective block swizzle: each XCD owns exactly one (b,chunk), so
// the chunk's K/V (1.5 MB) stays resident in that XCD's 4MB L2.
// Q=t, K=h (bf16x3), V=featT (bf16). S^T frags; softmax row in 4 lanes.
// grid 512 (1D), block 256 = 4 waves sharing the LDS tiles.
__global__ __launch_bounds__(256, 2) void k_flash(
    const u16* t_hi, const u16* t_lo, const u16* h_hi, const u16* h_lo,
    const u16* featT, const float* ax, const float* ay, const u64* maskp,
    float* PO, float* m_ws, float* l_ws) {
  // XCD swizzle: hw sends id%8 to XCD (id%8); give each XCD a contiguous
  // 64-range = one full (b,chunk) worth of row-tiles.
  int id = blockIdx.x;                       // 0..511
  int wg = (id & 7) * 64 + (id >> 3);        // bijective (512 % 8 == 0)
  int b = wg >> 8;
  int rem = wg & 255;
  int chunk = rem >> 6;
  int it = rem & 63;

  int t = threadIdx.x;
  int wid = t >> 6, lane = t & 63;
  int li = lane & 15, lg = lane >> 4;
  int i = it * 64 + wid * 16 + li;            // this lane's query row
  size_t browQ = (size_t)b * NN + i;

  __shared__ __align__(16) u16 Kh[KSTEP * 256];   // 16 KB, swizzled
  __shared__ __align__(16) u16 Kl[KSTEP * 256];   // 16 KB
  __shared__ __align__(16) u16 Vs[256 * KSTEP];   // 16 KB, swizzled
  __shared__ __align__(16) u16 Pbuf[4][16][40];   // per-wave P exchange

  short8 qhi[8], qlo[8];
  {
    const u16* qp = t_hi + browQ * DD + lg * 8;
    const u16* qp2 = t_lo + browQ * DD + lg * 8;
    #pragma unroll
    for (int ks = 0; ks < 8; ks++) {
      qhi[ks] = *(const short8*)(qp + ks * 32);
      qlo[ks] = *(const short8*)(qp2 + ks * 32);
    }
  }
  float ayv = ay[browQ];
  const float* axp = ax + (size_t)b * NN;
  const u32* mrow = (const u32*)maskp + browQ * (NN / 32);
  const u16* kh_src = h_hi + ((size_t)b * NN + chunk * CHUNKLEN) * DD;
  const u16* kl_src = h_lo + ((size_t)b * NN + chunk * CHUNKLEN) * DD;
  const u16* v_src = featT + (size_t)b * DD * NN + chunk * CHUNKLEN;

  floatx4 acc[16];
  #pragma unroll
  for (int df = 0; df < 16; df++) acc[df] = 0.f;
  float m_run = -INFINITY, l_run = 0.f;

  // staging registers (tile jt in flight)
  intx4 sKh[4], sKl[4], sVv[4];
  {
    int r = (t >> 5), c8 = (t & 31) * 8;
    int dv = (t >> 2), cv = (t & 3) * 8;
    #pragma unroll
    for (int s = 0; s < 4; s++) {
      sKh[s] = *(const intx4*)(kh_src + (size_t)(s * 8 + r) * DD + c8);
      sKl[s] = *(const intx4*)(kl_src + (size_t)(s * 8 + r) * DD + c8);
      sVv[s] = *(const intx4*)(v_src + (size_t)(s * 64 + dv) * NN + cv);
    }
  }

  for (int jt = 0; jt < STEPS; jt++) {
    __syncthreads();  // all waves done reading previous tile
    {
      int r0 = (t >> 5), c8 = (t & 31) * 8;
      int dv0 = (t >> 2), cv = (t & 3) * 8;
      #pragma unroll
      for (int s = 0; s < 4; s++) {
        int r = s * 8 + r0;
        int off = r * 256 + (c8 ^ ((r & 7) << 3));
        *(intx4*)(Kh + off) = sKh[s];
        *(intx4*)(Kl + off) = sKl[s];
        int d = s * 64 + dv0;
        *(intx4*)(Vs + d * KSTEP + (cv ^ (((d >> 1) & 3) << 3))) = sVv[s];
      }
    }
    __syncthreads();  // tile ready
    int j0 = jt * KSTEP;  // within-chunk
    if (jt + 1 < STEPS) {  // issue next-tile loads; they fly under compute
      const u16* kh2 = kh_src + (size_t)(j0 + KSTEP) * DD;
      const u16* kl2 = kl_src + (size_t)(j0 + KSTEP) * DD;
      int r = (t >> 5), c8 = (t & 31) * 8;
      int dv = (t >> 2), cv = (t & 3) * 8;
      #pragma unroll
      for (int s = 0; s < 4; s++) {
        sKh[s] = *(const intx4*)(kh2 + (size_t)(s * 8 + r) * DD + c8);
        sKl[s] = *(const intx4*)(kl2 + (size_t)(s * 8 + r) * DD + c8);
        sVv[s] = *(const intx4*)(v_src + (size_t)(s * 64 + dv) * NN + (j0 + KSTEP) + cv);
      }
    }

    int ja = chunk * CHUNKLEN + j0;  // absolute column
    u32 M = mrow[ja >> 5];
    floatx4 axv[2];
    axv[0] = *(const floatx4*)(axp + ja + lg * 4);
    axv[1] = *(const floatx4*)(axp + ja + 16 + lg * 4);

    // ---- S^T = K . Q^T  (bf16x3) from LDS ----
    floatx4 sacc[2];
    sacc[0] = 0.f; sacc[1] = 0.f;
    #pragma unroll
    for (int ks = 0; ks < 8; ks++) {
      #pragma unroll
      for (int fi = 0; fi < 2; fi++) {
        int row = fi * 16 + li;
        int off = row * 256 + ((ks * 32 + lg * 8) ^ ((row & 7) << 3));
        short8 a0 = *(const short8*)(Kh + off);
        short8 a1 = *(const short8*)(Kl + off);
        sacc[fi] = mfma16(a0, qhi[ks], sacc[fi]);
        sacc[fi] = mfma16(a1, qhi[ks], sacc[fi]);
        sacc[fi] = mfma16(a0, qlo[ks], sacc[fi]);
      }
    }
    // ---- bias + lrelu + mask; online softmax ----
    float sv[2][4];
    float m_tile = -INFINITY;
    #pragma unroll
    for (int fi = 0; fi < 2; fi++) {
      u32 nib = (M >> (fi * 16 + lg * 4)) & 0xFu;
      #pragma unroll
      for (int r = 0; r < 4; r++) {
        float s = sacc[fi][r] + axv[fi][r] + ayv;
        s = lrelu(s);
        s = (nib >> r) & 1u ? s : NEGINF;
        sv[fi][r] = s;
        m_tile = fmaxf(m_tile, s);
      }
    }
    m_tile = fmaxf(m_tile, __shfl_xor(m_tile, 16));
    m_tile = fmaxf(m_tile, __shfl_xor(m_tile, 32));
    bool nores = __all(m_tile <= m_run);  // exact skip: max unchanged
    if (!nores) {
      float m_new = fmaxf(m_run, m_tile);
      float scale = __expf(m_run - m_new);
      l_run *= scale;
      #pragma unroll
      for (int df = 0; df < 16; df++) acc[df] *= scale;
      m_run = m_new;
    }

    float psum = 0.f;
    #pragma unroll
    for (int fi = 0; fi < 2; fi++) {
      u16 pb[4];
      #pragma unroll
      for (int r = 0; r < 4; r++) {
        float p = __expf(sv[fi][r] - m_run);
        pb[r] = f2bf(p);
        psum += bf2f(pb[r]);
      }
      u32 w0 = (u32)pb[0] | ((u32)pb[1] << 16);
      u32 w1 = (u32)pb[2] | ((u32)pb[3] << 16);
      *(uint2*)&Pbuf[wid][li][fi * 16 + lg * 4] = make_uint2(w0, w1);
    }
    psum += __shfl_xor(psum, 16);
    psum += __shfl_xor(psum, 32);
    l_run += psum;

    // ---- PV: O^T += V^T . P^T  (V from LDS) ----
    short8 pf = *(const short8*)&Pbuf[wid][li][lg * 8];
    #pragma unroll
    for (int df = 0; df < 16; df++) {
      int d = df * 16 + li;
      short8 vf = *(const short8*)(Vs + d * KSTEP + ((lg * 8) ^ (((d >> 1) & 3) << 3)));
      acc[df] = mfma16(vf, pf, acc[df]);
    }
  }

  // ---- partials out: PO[b][chunk][i][d], float4 per (df) ----
  size_t pobase = ((size_t)(b * NCHUNK + chunk) * NN + i) * DD;
  #pragma unroll
  for (int df = 0; df < 16; df++)
    *(floatx4*)(PO + pobase + df * 16 + lg * 4) = acc[df];
  if (lg == 0) {
    size_t mi = ((size_t)b * NCHUNK + chunk) * NN + i;
    m_ws[mi] = m_run;
    l_ws[mi] = l_run;
  }
}

// ---------------------------------------------------------------------------
// K5: combine NCHUNK partials -> h_prime row (registers) -> BiInteraction MLP
// -> c (hi/lo bf16). Weights pre-transposed so loads coalesce.
// grid (1024,2), block 256 (wave per row).
__global__ void k_combine_mlp(const float* PO, const float* m_ws,
                              const float* l_ws, const float* feat,
                              const float* e1t, const float* e1b,
                              const float* e2t, const float* e2b,
                              const float* i0w, const float* i0b,
                              u16* c_hi, u16* c_lo) {
  int b = blockIdx.y;
  int t = threadIdx.x;
  int i = blockIdx.x * 4 + (t >> 6);
  int lane = t & 63;
  int d4 = lane * 4;
  size_t row = (size_t)b * NN + i;

  // ---- combine ----
  float mc[NCHUNK], lc[NCHUNK];
  #pragma unroll
  for (int c = 0; c < NCHUNK; c++) {
    mc[c] = m_ws[((size_t)b * NCHUNK + c) * NN + i];
    lc[c] = l_ws[((size_t)b * NCHUNK + c) * NN + i];
  }
  float M = -INFINITY;
  #pragma unroll
  for (int c = 0; c < NCHUNK; c++) M = fmaxf(M, mc[c]);
  float w[NCHUNK], L = 0.f;
  #pragma unroll
  for (int c = 0; c < NCHUNK; c++) { w[c] = __expf(mc[c] - M); L += w[c] * lc[c]; }
  float invL = 1.f / L;

  floatx4 hv = 0.f;
  #pragma unroll
  for (int c = 0; c < NCHUNK; c++) {
    floatx4 v = *(const floatx4*)(PO + ((size_t)(b * NCHUNK + c) * NN + i) * DD + d4);
    hv += w[c] * v;
  }
  hv *= invL;  // h_prime[row][d4..d4+3], stays in registers

  // ---- BiInteraction MLP (coalesced transposed weights) ----
  floatx4 fv = *(const floatx4*)(feat + row * DD + d4);
  float p1[16], p2[16];
  #pragma unroll
  for (int o = 0; o < 16; o++) {
    floatx4 w1 = *(const floatx4*)(e1t + o * 256 + d4);
    floatx4 w2 = *(const floatx4*)(e2t + o * 256 + d4);
    p1[o] = fv[0] * w1[0] + fv[1] * w1[1] + fv[2] * w1[2] + fv[3] * w1[3];
    p2[o] = hv[0] * w2[0] + hv[1] * w2[1] + hv[2] * w2[2] + hv[3] * w2[3];
  }
  #pragma unroll
  for (int off = 32; off; off >>= 1) {
    #pragma unroll
    for (int o = 0; o < 16; o++) {
      p1[o] += __shfl_xor(p1[o], off);
      p2[o] += __shfl_xor(p2[o], off);
    }
  }
  float cc[32];
  #pragma unroll
  for (int o = 0; o < 16; o++) {
    cc[o] = lrelu(p1[o] + e1b[o]);
    cc[16 + o] = lrelu(p2[o] + e2b[o]);
  }
  #pragma unroll
  for (int q = 0; q < 4; q++) {
    int o2 = q * 64 + lane;
    float s = i0b[o2];
    #pragma unroll
    for (int k = 0; k < 32; k++) s += cc[k] * i0w[(size_t)k * 256 + o2];
    s = lrelu(s);
    u16 hb = f2bf(s);
    c_hi[row * DD + o2] = hb;
    c_lo[row * DD + o2] = f2bf(s - bf2f(hb));
  }
}

// ---------------------------------------------------------------------------
extern "C" void kernel_launch(void* const* d_in, const int* in_sizes, int n_in,
                              void* d_out, int out_size, void* d_ws,
                              size_t ws_size, hipStream_t stream) {
  const float* feat = (const float*)d_in[0];
  const int* adj = (const int*)d_in[1];
  const float* W = (const float*)d_in[2];
  const float* a1 = (const float*)d_in[3];
  const float* a2 = (const float*)d_in[4];
  const float* a12 = (const float*)d_in[5];
  const float* e1w = (const float*)d_in[6];
  const float* e1b = (const float*)d_in[7];
  const float* e2w = (const float*)d_in[8];
  const float* e2b = (const float*)d_in[9];
  const float* i0w = (const float*)d_in[10];
  const float* i0b = (const float*)d_in[11];
  const float* i1w = (const float*)d_in[12];
  const float* i1b = (const float*)d_in[13];
  float* out = (float*)d_out;

  char* p = (char*)d_ws;
  auto carve = [&](size_t bytes) -> char* {
    char* r = p;
    p += (bytes + 255) & ~(size_t)255;
    return r;
  };
  const size_t MAT = 256 * 256 * sizeof(u16);             // 128 KB
  const size_t BND = (size_t)BB * NN * DD * sizeof(u16);  // 4 MB
  u16* WThi = (u16*)carve(MAT);
  u16* WTlo = (u16*)carve(MAT);
  u16* A12Thi = (u16*)carve(MAT);
  u16* A12Tlo = (u16*)carve(MAT);
  u16* I1Thi = (u16*)carve(MAT);
  u16* I1Tlo = (u16*)carve(MAT);
  u16* h_hi = (u16*)carve(BND);
  u16* h_lo = (u16*)carve(BND);
  u16* t_hi = (u16*)carve(BND);
  u16* t_lo = (u16*)carve(BND);
  u16* featT = (u16*)carve(BND);
  float* ax = (float*)carve((size_t)BB * NN * 4);
  float* ay = (float*)carve((size_t)BB * NN * 4);
  u64* maskp = (u64*)carve((size_t)BB * NN * (NN / 64) * 8);     // 4.2 MB
  float* PO = (float*)carve((size_t)BB * NCHUNK * NN * DD * 4);  // 33.5 MB
  float* m_ws = (float*)carve((size_t)BB * NCHUNK * NN * 4);
  float* l_ws = (float*)carve((size_t)BB * NCHUNK * NN * 4);
  float* e1t = (float*)carve(256 * 16 * 4);
  float* e2t = (float*)carve(256 * 16 * 4);
  u16* c_hi = (u16*)carve(BND);
  u16* c_lo = (u16*)carve(BND);

  k_adjpack<<<32768, 256, 0, stream>>>(adj, maskp);
  k_prep_w<<<dim3(8, 8, 3), dim3(32, 8), 0, stream>>>(
      W, a12, i1w, WThi, WTlo, A12Thi, A12Tlo, I1Thi, I1Tlo);
  k_prep_e<<<2, 256, 0, stream>>>(e1w, e2w, e1t, e2t);
  k_gemm<0, 0><<<dim3(128, 8), 256, 0, stream>>>(
      feat, nullptr, nullptr, WThi, WTlo, h_hi, h_lo, nullptr, nullptr);
  k_axay<<<2048, 256, 0, stream>>>(h_hi, h_lo, a1, a2, ax, ay);
  k_gemm<1, 0><<<dim3(128, 8), 256, 0, stream>>>(
      nullptr, h_hi, h_lo, A12Thi, A12Tlo, t_hi, t_lo, nullptr, nullptr);
  k_featT<<<dim3(64, 4, 2), 256, 0, stream>>>(feat, featT);
  k_flash<<<512, 256, 0, stream>>>(
      t_hi, t_lo, h_hi, h_lo, featT, ax, ay, maskp, PO, m_ws, l_ws);
  k_combine_mlp<<<dim3(1024, 2), 256, 0, stream>>>(
      PO, m_ws, l_ws, feat, e1t, e1b, e2t, e2b, i0w, i0b, c_hi, c_lo);
  k_gemm<1, 1><<<dim3(128, 8), 256, 0, stream>>>(
      nullptr, c_hi, c_lo, I1Thi, I1Tlo, nullptr, nullptr, out, i1b);
}